// Round 2
// baseline (640.066 us; speedup 1.0000x reference)
//
#include <hip/hip_runtime.h>
#include <hip/hip_fp16.h>
#include <stdint.h>

#define V_N   50257
#define V_PAD 50304     // padded rows for B (multiple of 128)
#define NFRQ  256
#define NCH   1024
#define MT    4096      // B*S
#define KC    512       // 2*N_FREQ
#define TWO_PI 6.28318530717958647692f

typedef _Float16 f16;
typedef __attribute__((ext_vector_type(8))) _Float16 f16x8;
typedef __attribute__((ext_vector_type(4))) float    f32x4;

// async global->LDS, 16B per lane; LDS dest = wave-uniform base + lane*16
__device__ __forceinline__ void gload_lds16(const void* g, const void* l) {
  typedef const __attribute__((address_space(1))) unsigned int* gp_t;
  typedef __attribute__((address_space(3))) unsigned int* lp_t;
  __builtin_amdgcn_global_load_lds((gp_t)(uint64_t)(uintptr_t)g,
                                   (lp_t)(uint32_t)(uintptr_t)l, 16, 0, 0);
}

// ---------------- Kernel 0: B_ws[t][k] trig table, t-major ---------------------------
// B[t][2(f-1)+e] = e ? -sin(2pi f t / V) : cos(2pi f t / V), f = k/2+1.
// One thread per 16B chunk (8 f16 = 4 freqs); rows t >= V_N zero-padded.
__global__ __launch_bounds__(256) void k0_genB(f16* __restrict__ B) {
  int gid = blockIdx.x * 256 + threadIdx.x;
  int t = gid >> 6, q = gid & 63;
  f16x8 pk;
  if (t < V_N) {
    const float w0 = TWO_PI / (float)V_N;
#pragma unroll
    for (int p = 0; p < 4; ++p) {
      int f = 4 * q + p + 1;
      int m = (f * t) % V_N;          // f*t <= 256*50256 fits int32
      float sn, cs;
      __sincosf(w0 * (float)m, &sn, &cs);
      pk[2 * p]     = (f16)cs;
      pk[2 * p + 1] = (f16)(-sn);
    }
  } else {
#pragma unroll
    for (int j = 0; j < 8; ++j) pk[j] = (f16)0.f;
  }
  *(f16x8*)&B[(size_t)t * KC + q * 8] = pk;
}

// ---------------- Kernel 1: A[m][2f+e] = (e? Yi : Yr)[m][f],  Y = h @ w -------------
__global__ __launch_bounds__(256) void k1_proj(
    const float* __restrict__ h, const float* __restrict__ w, f16* __restrict__ A) {
  __shared__ __align__(16) f16 As[64 * 64];
  __shared__ __align__(16) f16 Bs[64 * 64];
  const int tid = threadIdx.x;
  const int bn0 = blockIdx.x * 64;
  const int bm0 = blockIdx.y * 64;
  const int lane = tid & 63, wid = tid >> 6;
  const int lr = lane & 15, lg = lane >> 4;
  const int wr = wid >> 1, wc = wid & 1;

  f32x4 acc[2][2];
#pragma unroll
  for (int i = 0; i < 2; ++i)
#pragma unroll
    for (int j = 0; j < 2; ++j) acc[i][j] = (f32x4){0.f, 0.f, 0.f, 0.f};

  for (int s = 0; s < NCH / 64; ++s) {
    const int k0 = s * 64;
    __syncthreads();
#pragma unroll
    for (int r = 0; r < 2; ++r) {
      int q = tid + r * 256;
      int m = q >> 3, c = q & 7;
      const float* src = h + (size_t)(bm0 + m) * NCH + k0 + c * 8;
      f32x4 v0 = *(const f32x4*)src;
      f32x4 v1 = *(const f32x4*)(src + 4);
      f16x8 pk;
#pragma unroll
      for (int e = 0; e < 4; ++e) { pk[e] = (f16)v0[e]; pk[4 + e] = (f16)v1[e]; }
      *(f16x8*)&As[m * 64 + ((c ^ (m & 7)) << 3)] = pk;
    }
#pragma unroll
    for (int r = 0; r < 2; ++r) {
      int q = tid + r * 256;
      int c = q >> 6, n = q & 63;
      int jj = bn0 + n;
      int wcol = (jj >> 1) + ((jj & 1) ? NFRQ : 0);
      f16x8 pk;
#pragma unroll
      for (int j = 0; j < 8; ++j)
        pk[j] = (f16)w[(size_t)(k0 + c * 8 + j) * KC + wcol];
      *(f16x8*)&Bs[n * 64 + ((c ^ (n & 7)) << 3)] = pk;
    }
    __syncthreads();
#pragma unroll
    for (int kk = 0; kk < 2; ++kk) {
      const int cb = kk * 4 + lg;
      f16x8 a[2], b[2];
#pragma unroll
      for (int mi = 0; mi < 2; ++mi) {
        int row = wr * 32 + mi * 16 + lr;
        a[mi] = *(const f16x8*)&As[row * 64 + ((cb ^ (row & 7)) << 3)];
      }
#pragma unroll
      for (int ni = 0; ni < 2; ++ni) {
        int col = wc * 32 + ni * 16 + lr;
        b[ni] = *(const f16x8*)&Bs[col * 64 + ((cb ^ (col & 7)) << 3)];
      }
#pragma unroll
      for (int mi = 0; mi < 2; ++mi)
#pragma unroll
        for (int ni = 0; ni < 2; ++ni)
          acc[mi][ni] = __builtin_amdgcn_mfma_f32_16x16x32_f16(a[mi], b[ni], acc[mi][ni], 0, 0, 0);
    }
  }
#pragma unroll
  for (int mi = 0; mi < 2; ++mi)
#pragma unroll
    for (int ni = 0; ni < 2; ++ni)
#pragma unroll
      for (int r = 0; r < 4; ++r) {
        int row = bm0 + wr * 32 + mi * 16 + lg * 4 + r;
        int col = bn0 + wc * 32 + ni * 16 + lr;
        A[(size_t)row * KC + col] = (f16)acc[mi][ni][r];
      }
}

// ---------------- Kernel 2 (main): out = A @ B_ws^T-ish, both staged via gload_lds ---
// m97 structure: 128x128 tile, BK=64, 4 waves, 2-barrier loop, source-side swizzle.
// 1D grid with bijective XCD swizzle; n-panel-major so same-XCD blocks share B panel.
__global__ __launch_bounds__(256) void k2_pre(
    const f16* __restrict__ A, const f16* __restrict__ B, float* __restrict__ out) {
  __shared__ __align__(16) f16 As[128 * 64];
  __shared__ __align__(16) f16 Bs[128 * 64];
  const int tid = threadIdx.x;
  // XCD-aware bijective swizzle: nwg = 12576 = 8 * 1572
  const int orig = blockIdx.x;
  const int wgid = (orig & 7) * 1572 + (orig >> 3);
  const int bx = wgid >> 5;        // 0..392  (n panel)
  const int by = wgid & 31;        // 0..31   (m panel)
  const int bn0 = bx * 128;
  const int bm0 = by * 128;
  const int lane = tid & 63, wid = tid >> 6;
  const int lr = lane & 15, lg = lane >> 4;
  const int wr = wid >> 1, wc = wid & 1;

  f32x4 acc[4][4];
#pragma unroll
  for (int i = 0; i < 4; ++i)
#pragma unroll
    for (int j = 0; j < 4; ++j) acc[i][j] = (f32x4){0.f, 0.f, 0.f, 0.f};

  for (int s = 0; s < KC / 64; ++s) {
    __syncthreads();
    // stage A and B tiles: 16 chunks each of 64 lanes x 16B, source pre-swizzled
#pragma unroll
    for (int ii = 0; ii < 4; ++ii) {
      int i = wid * 4 + ii;
      int q = i * 64 + lane;
      int m = q >> 3, cl = q & 7;
      int cg = cl ^ (m & 7);
      gload_lds16(A + (size_t)(bm0 + m) * KC + s * 64 + cg * 8, &As[i * 512]);
    }
#pragma unroll
    for (int ii = 0; ii < 4; ++ii) {
      int i = wid * 4 + ii;
      int q = i * 64 + lane;
      int n = q >> 3, cl = q & 7;
      int cg = cl ^ (n & 7);
      gload_lds16(B + (size_t)(bn0 + n) * KC + s * 64 + cg * 8, &Bs[i * 512]);
    }
    __syncthreads();
#pragma unroll
    for (int kk = 0; kk < 2; ++kk) {
      const int cb = kk * 4 + lg;
      f16x8 a[4], b[4];
#pragma unroll
      for (int mi = 0; mi < 4; ++mi) {
        int row = wr * 64 + mi * 16 + lr;
        a[mi] = *(const f16x8*)&As[row * 64 + ((cb ^ (row & 7)) << 3)];
      }
#pragma unroll
      for (int ni = 0; ni < 4; ++ni) {
        int col = wc * 64 + ni * 16 + lr;
        b[ni] = *(const f16x8*)&Bs[col * 64 + ((cb ^ (col & 7)) << 3)];
      }
#pragma unroll
      for (int mi = 0; mi < 4; ++mi)
#pragma unroll
        for (int ni = 0; ni < 4; ++ni)
          acc[mi][ni] = __builtin_amdgcn_mfma_f32_16x16x32_f16(a[mi], b[ni], acc[mi][ni], 0, 0, 0);
    }
  }
  const float scale = 2.0f / (float)V_N;
#pragma unroll
  for (int ni = 0; ni < 4; ++ni) {
    int col = bn0 + wc * 64 + ni * 16 + lr;
    if (col < V_N) {
#pragma unroll
      for (int mi = 0; mi < 4; ++mi)
#pragma unroll
        for (int r = 0; r < 4; ++r) {
          int row = bm0 + wr * 64 + mi * 16 + lg * 4 + r;
          out[(size_t)row * V_N + col] = acc[mi][ni][r] * scale;
        }
    }
  }
}

// ---------------- Fallback kernel 2: on-the-fly B generation (R0, proven) ------------
__global__ __launch_bounds__(256) void k2_synth_otf(
    const f16* __restrict__ A, float* __restrict__ out) {
  __shared__ __align__(16) f16 As[128 * 64];
  __shared__ __align__(16) f16 Bs[128 * 64];
  const int tid = threadIdx.x;
  const int bn0 = blockIdx.x * 128;
  const int bm0 = blockIdx.y * 128;
  const int lane = tid & 63, wid = tid >> 6;
  const int lr = lane & 15, lg = lane >> 4;
  const int wr = wid >> 1, wc = wid & 1;

  const int nloc = tid & 127;
  const int g = tid >> 7;
  const int t = bn0 + nloc;
  const float w0 = TWO_PI / (float)V_N;
  float cr, ci, r1c, r1s, r17c, r17s;
  {
    int a1 = (int)(((long long)(16 * g + 1) * t) % V_N);
    int a2 = (int)((long long)t % V_N);
    int a3 = (int)(((long long)17 * t) % V_N);
    __sincosf((float)a1 * w0, &ci, &cr);
    __sincosf((float)a2 * w0, &r1s, &r1c);
    __sincosf((float)a3 * w0, &r17s, &r17c);
  }

  f32x4 acc[4][4];
#pragma unroll
  for (int i = 0; i < 4; ++i)
#pragma unroll
    for (int j = 0; j < 4; ++j) acc[i][j] = (f32x4){0.f, 0.f, 0.f, 0.f};

  for (int s = 0; s < KC / 64; ++s) {
    f16x8 bch[4];
#pragma unroll
    for (int u = 0; u < 4; ++u)
#pragma unroll
      for (int p = 0; p < 4; ++p) {
        bch[u][2 * p]     = (f16)cr;
        bch[u][2 * p + 1] = (f16)(-ci);
        float rc = (u == 3 && p == 3) ? r17c : r1c;
        float rs = (u == 3 && p == 3) ? r17s : r1s;
        float nc = cr * rc - ci * rs;
        float ns = cr * rs + ci * rc;
        cr = nc; ci = ns;
      }
    __syncthreads();
#pragma unroll
    for (int ii = 0; ii < 4; ++ii) {
      int i = wid * 4 + ii;
      int q = i * 64 + lane;
      int m = q >> 3, cl = q & 7;
      int cg = cl ^ (m & 7);
      gload_lds16(A + (size_t)(bm0 + m) * KC + s * 64 + cg * 8, &As[i * 512]);
    }
#pragma unroll
    for (int u = 0; u < 4; ++u) {
      int c = 4 * g + u;
      *(f16x8*)&Bs[nloc * 64 + ((c ^ (nloc & 7)) << 3)] = bch[u];
    }
    __syncthreads();
#pragma unroll
    for (int kk = 0; kk < 2; ++kk) {
      const int cb = kk * 4 + lg;
      f16x8 a[4], b[4];
#pragma unroll
      for (int mi = 0; mi < 4; ++mi) {
        int row = wr * 64 + mi * 16 + lr;
        a[mi] = *(const f16x8*)&As[row * 64 + ((cb ^ (row & 7)) << 3)];
      }
#pragma unroll
      for (int ni = 0; ni < 4; ++ni) {
        int col = wc * 64 + ni * 16 + lr;
        b[ni] = *(const f16x8*)&Bs[col * 64 + ((cb ^ (col & 7)) << 3)];
      }
#pragma unroll
      for (int mi = 0; mi < 4; ++mi)
#pragma unroll
        for (int ni = 0; ni < 4; ++ni)
          acc[mi][ni] = __builtin_amdgcn_mfma_f32_16x16x32_f16(a[mi], b[ni], acc[mi][ni], 0, 0, 0);
    }
  }
  const float scale = 2.0f / (float)V_N;
#pragma unroll
  for (int ni = 0; ni < 4; ++ni) {
    int col = bn0 + wc * 64 + ni * 16 + lr;
    if (col < V_N) {
#pragma unroll
      for (int mi = 0; mi < 4; ++mi)
#pragma unroll
        for (int r = 0; r < 4; ++r) {
          int row = bm0 + wr * 64 + mi * 16 + lg * 4 + r;
          out[(size_t)row * V_N + col] = acc[mi][ni][r] * scale;
        }
    }
  }
}

extern "C" void kernel_launch(void* const* d_in, const int* in_sizes, int n_in,
                              void* d_out, int out_size, void* d_ws, size_t ws_size,
                              hipStream_t stream) {
  const float* h = (const float*)d_in[0];
  const float* w = (const float*)d_in[1];
  float* out = (float*)d_out;

  const size_t B_BYTES = (size_t)V_PAD * KC * sizeof(f16);   // 51,511,296
  const size_t A_BYTES = (size_t)MT * KC * sizeof(f16);      //  4,194,304
  dim3 blk(256);

  if (ws_size >= B_BYTES + A_BYTES) {
    f16* Bt = (f16*)d_ws;
    f16* A  = (f16*)((char*)d_ws + B_BYTES);
    hipLaunchKernelGGL(k0_genB, dim3((V_PAD * 64) / 256), blk, 0, stream, Bt);
    hipLaunchKernelGGL(k1_proj, dim3(KC / 64, MT / 64), blk, 0, stream, h, w, A);
    hipLaunchKernelGGL(k2_pre, dim3(393 * 32), blk, 0, stream, A, Bt, out);
  } else {
    f16* A = (f16*)d_ws;
    hipLaunchKernelGGL(k1_proj, dim3(KC / 64, MT / 64), blk, 0, stream, h, w, A);
    hipLaunchKernelGGL(k2_synth_otf, dim3((V_N + 127) / 128, MT / 128), blk, 0, stream, A, out);
  }
}

// Round 3
// 498.011 us; speedup vs baseline: 1.2852x; 1.2852x over previous
//
#include <hip/hip_runtime.h>
#include <hip/hip_fp16.h>
#include <stdint.h>

#define V_N   50257
#define NPAN  197                    // ceil(V_N/256)
#define V_PAD (NPAN * 256)           // 50432
#define NCH   1024
#define MT    4096                   // B*S
#define KC    512                    // 2*N_FREQ
#define NFRQ  256
#define TWO_PI 6.28318530717958647692f

typedef _Float16 f16;
typedef __attribute__((ext_vector_type(8))) _Float16 f16x8;
typedef __attribute__((ext_vector_type(4))) float    f32x4;

// async global->LDS, 16B per lane; LDS dest = wave-uniform base + lane*16
__device__ __forceinline__ void gload_lds16(const void* g, const void* l) {
  typedef const __attribute__((address_space(1))) unsigned int* gp_t;
  typedef __attribute__((address_space(3))) unsigned int* lp_t;
  __builtin_amdgcn_global_load_lds((gp_t)(uint64_t)(uintptr_t)g,
                                   (lp_t)(uint32_t)(uintptr_t)l, 16, 0, 0);
}

// ---------------- Kernel 0: B_ws[t][k] trig table, t-major ---------------------------
__global__ __launch_bounds__(256) void k0_genB(f16* __restrict__ B) {
  int gid = blockIdx.x * 256 + threadIdx.x;
  int t = gid >> 6, q = gid & 63;
  if (t >= V_PAD) return;
  f16x8 pk;
  if (t < V_N) {
    const float w0 = TWO_PI / (float)V_N;
#pragma unroll
    for (int p = 0; p < 4; ++p) {
      int f = 4 * q + p + 1;
      int m = (f * t) % V_N;          // exact: f*t <= 256*50256 < 2^24? no, < 2^31 ok in int
      float sn, cs;
      __sincosf(w0 * (float)m, &sn, &cs);
      pk[2 * p]     = (f16)cs;
      pk[2 * p + 1] = (f16)(-sn);
    }
  } else {
#pragma unroll
    for (int j = 0; j < 8; ++j) pk[j] = (f16)0.f;
  }
  *(f16x8*)&B[(size_t)t * KC + q * 8] = pk;
}

// ---------------- Kernel 1: A[m][2f+e] = (e? Yi : Yr)[m][f],  Y = h @ w -------------
__global__ __launch_bounds__(256) void k1_proj(
    const float* __restrict__ h, const float* __restrict__ w, f16* __restrict__ A) {
  __shared__ __align__(16) f16 As[64 * 64];
  __shared__ __align__(16) f16 Bs[64 * 64];
  const int tid = threadIdx.x;
  const int bn0 = blockIdx.x * 64;
  const int bm0 = blockIdx.y * 64;
  const int lane = tid & 63, wid = tid >> 6;
  const int lr = lane & 15, lg = lane >> 4;
  const int wr = wid >> 1, wc = wid & 1;

  f32x4 acc[2][2];
#pragma unroll
  for (int i = 0; i < 2; ++i)
#pragma unroll
    for (int j = 0; j < 2; ++j) acc[i][j] = (f32x4){0.f, 0.f, 0.f, 0.f};

  for (int s = 0; s < NCH / 64; ++s) {
    const int k0 = s * 64;
    __syncthreads();
#pragma unroll
    for (int r = 0; r < 2; ++r) {
      int q = tid + r * 256;
      int m = q >> 3, c = q & 7;
      const float* src = h + (size_t)(bm0 + m) * NCH + k0 + c * 8;
      f32x4 v0 = *(const f32x4*)src;
      f32x4 v1 = *(const f32x4*)(src + 4);
      f16x8 pk;
#pragma unroll
      for (int e = 0; e < 4; ++e) { pk[e] = (f16)v0[e]; pk[4 + e] = (f16)v1[e]; }
      *(f16x8*)&As[m * 64 + ((c ^ (m & 7)) << 3)] = pk;
    }
#pragma unroll
    for (int r = 0; r < 2; ++r) {
      int q = tid + r * 256;
      int c = q >> 6, n = q & 63;
      int jj = bn0 + n;
      int wcol = (jj >> 1) + ((jj & 1) ? NFRQ : 0);
      f16x8 pk;
#pragma unroll
      for (int j = 0; j < 8; ++j)
        pk[j] = (f16)w[(size_t)(k0 + c * 8 + j) * KC + wcol];
      *(f16x8*)&Bs[n * 64 + ((c ^ (n & 7)) << 3)] = pk;
    }
    __syncthreads();
#pragma unroll
    for (int kk = 0; kk < 2; ++kk) {
      const int cb = kk * 4 + lg;
      f16x8 a[2], b[2];
#pragma unroll
      for (int mi = 0; mi < 2; ++mi) {
        int row = wr * 32 + mi * 16 + lr;
        a[mi] = *(const f16x8*)&As[row * 64 + ((cb ^ (row & 7)) << 3)];
      }
#pragma unroll
      for (int ni = 0; ni < 2; ++ni) {
        int col = wc * 32 + ni * 16 + lr;
        b[ni] = *(const f16x8*)&Bs[col * 64 + ((cb ^ (col & 7)) << 3)];
      }
#pragma unroll
      for (int mi = 0; mi < 2; ++mi)
#pragma unroll
        for (int ni = 0; ni < 2; ++ni)
          acc[mi][ni] = __builtin_amdgcn_mfma_f32_16x16x32_f16(a[mi], b[ni], acc[mi][ni], 0, 0, 0);
    }
  }
#pragma unroll
  for (int mi = 0; mi < 2; ++mi)
#pragma unroll
    for (int ni = 0; ni < 2; ++ni)
#pragma unroll
      for (int r = 0; r < 4; ++r) {
        int row = bm0 + wr * 32 + mi * 16 + lg * 4 + r;
        int col = bn0 + wc * 32 + ni * 16 + lr;
        A[(size_t)row * KC + col] = (f16)acc[mi][ni][r];
      }
}

// ---------------- Kernel 2: 256x256 tile, 8 waves, BK=64, 8-phase counted-vmcnt ------
// Striped frag mapping: phase (mh,nh) reads only A-half(mh) + B-half(nh).
// Stage stream per K-tile kt: p0: A1(kt+1), p1: B1(kt+1), p2: A0(kt+2), p3: B0(kt+2).
// One vmcnt(6) per K-tile (3 half-tiles in flight); vmcnt(0) only at kt=7.

// stage one 128-row x 64-k half-tile (16 KB): 512 threads x 2 chunks of 16B
__device__ __forceinline__ void stage_half(const f16* __restrict__ M, int grow0,
                                           int kt, f16* dst, int tid) {
  int m  = tid >> 3;
  int cg = (tid & 7) ^ (m & 7);                 // source-side swizzle (rule #21)
  const f16* s = M + (size_t)(grow0 + m) * KC + kt * 64 + cg * 8;
  gload_lds16(s,                      dst + tid * 8);
  gload_lds16(s + (size_t)64 * KC,    dst + (tid + 512) * 8);   // rows m and m+64
}

__device__ __forceinline__ void read_afrags(const f16* base, int wm, int lr, int lg,
                                            f16x8 a[4][2]) {
#pragma unroll
  for (int j = 0; j < 4; ++j) {
    int hrow = (j * 2 + wm) * 16 + lr;
#pragma unroll
    for (int ks = 0; ks < 2; ++ks) {
      int c = ks * 4 + lg;
      a[j][ks] = *(const f16x8*)&base[hrow * 64 + ((c ^ (hrow & 7)) << 3)];
    }
  }
}
__device__ __forceinline__ void read_bfrags(const f16* base, int wn, int lr, int lg,
                                            f16x8 b[2][2]) {
#pragma unroll
  for (int i = 0; i < 2; ++i) {
    int hrow = (i * 4 + wn) * 16 + lr;
#pragma unroll
    for (int ks = 0; ks < 2; ++ks) {
      int c = ks * 4 + lg;
      b[i][ks] = *(const f16x8*)&base[hrow * 64 + ((c ^ (hrow & 7)) << 3)];
    }
  }
}

#define MFMA_QUAD(MH, NH, BV)                                                        \
  do {                                                                               \
    __builtin_amdgcn_s_setprio(1);                                                   \
    _Pragma("unroll") for (int j_ = 0; j_ < 4; ++j_)                                 \
    _Pragma("unroll") for (int i_ = 0; i_ < 2; ++i_)                                 \
    _Pragma("unroll") for (int ks_ = 0; ks_ < 2; ++ks_)                              \
      acc[(MH)*4 + j_][(NH)*2 + i_] = __builtin_amdgcn_mfma_f32_16x16x32_f16(        \
          a[j_][ks_], (BV)[i_][ks_], acc[(MH)*4 + j_][(NH)*2 + i_], 0, 0, 0);        \
    __builtin_amdgcn_s_setprio(0);                                                   \
  } while (0)

#define CFENCE asm volatile("" ::: "memory")

__global__ __launch_bounds__(512, 2) void k2_8ph(
    const f16* __restrict__ A, const f16* __restrict__ B, float* __restrict__ out) {
  __shared__ __align__(16) f16 Asl[2][2][128 * 64];   // [buf][half][row*64 + k]
  __shared__ __align__(16) f16 Bsl[2][2][128 * 64];
  const int tid = threadIdx.x;
  // XCD-aware bijective swizzle: nwg = 3152 = 8 * 394
  const int orig = blockIdx.x;
  const int wgid = (orig & 7) * 394 + (orig >> 3);
  const int bx = wgid >> 4;          // 0..196 (n panel), by-minor for B-panel L2 reuse
  const int by = wgid & 15;          // 0..15  (m panel)
  const int bn0 = bx << 8;
  const int bm0 = by << 8;
  const int lane = tid & 63, wid = tid >> 6;
  const int wm = wid >> 2, wn = wid & 3;      // 2M x 4N waves
  const int lr = lane & 15, lg = lane >> 4;

  f32x4 acc[8][4];
#pragma unroll
  for (int i = 0; i < 8; ++i)
#pragma unroll
    for (int j = 0; j < 4; ++j) acc[i][j] = (f32x4){0.f, 0.f, 0.f, 0.f};
  f16x8 a[4][2], bA[2][2], bB[2][2];

  // prologue: 6 half-tiles (kt0 complete + kt1 A0,B0)
  stage_half(A, bm0 + 0,   0, &Asl[0][0][0], tid);
  stage_half(B, bn0 + 0,   0, &Bsl[0][0][0], tid);
  stage_half(A, bm0 + 128, 0, &Asl[0][1][0], tid);
  stage_half(B, bn0 + 128, 0, &Bsl[0][1][0], tid);
  stage_half(A, bm0 + 0,   1, &Asl[1][0][0], tid);
  stage_half(B, bn0 + 0,   1, &Bsl[1][0][0], tid);

  for (int kt = 0; kt < 8; ++kt) {
    const int buf = kt & 1;
    // ---- phase 0: stage A1(kt+1); wait; reads (12); MFMA (0,0) ----
    if (kt + 1 < 8) stage_half(A, bm0 + 128, kt + 1, &Asl[buf ^ 1][1][0], tid);
    if (kt < 7) asm volatile("s_waitcnt vmcnt(6)" ::: "memory");
    else        asm volatile("s_waitcnt vmcnt(0)" ::: "memory");
    __builtin_amdgcn_s_barrier();
    CFENCE;
    read_afrags(&Asl[buf][0][0], wm, lr, lg, a);
    read_bfrags(&Bsl[buf][0][0], wn, lr, lg, bA);
    MFMA_QUAD(0, 0, bA);
    CFENCE;
    __builtin_amdgcn_s_barrier();
    // ---- phase 1: reads B1 (4); stage B1(kt+1); MFMA (0,1) ----
    CFENCE;
    read_bfrags(&Bsl[buf][1][0], wn, lr, lg, bB);
    if (kt + 1 < 8) stage_half(B, bn0 + 128, kt + 1, &Bsl[buf ^ 1][1][0], tid);
    CFENCE;
    __builtin_amdgcn_s_barrier();
    MFMA_QUAD(0, 1, bB);
    CFENCE;
    __builtin_amdgcn_s_barrier();
    // ---- phase 2: reads A1 (8); stage A0(kt+2); MFMA (1,0) ----
    CFENCE;
    read_afrags(&Asl[buf][1][0], wm, lr, lg, a);
    if (kt + 2 < 8) stage_half(A, bm0 + 0, kt + 2, &Asl[buf][0][0], tid);
    CFENCE;
    __builtin_amdgcn_s_barrier();
    MFMA_QUAD(1, 0, bA);
    CFENCE;
    __builtin_amdgcn_s_barrier();
    // ---- phase 3: stage B0(kt+2); MFMA (1,1) ----
    if (kt + 2 < 8) stage_half(B, bn0 + 0, kt + 2, &Bsl[buf][0][0], tid);
    CFENCE;
    __builtin_amdgcn_s_barrier();
    MFMA_QUAD(1, 1, bB);
    CFENCE;
    __builtin_amdgcn_s_barrier();
  }

  const float scale = 2.0f / (float)V_N;
#pragma unroll
  for (int nh = 0; nh < 2; ++nh)
#pragma unroll
    for (int i = 0; i < 2; ++i) {
      int col = bn0 + nh * 128 + (i * 4 + wn) * 16 + lr;
      if (col < V_N) {
#pragma unroll
        for (int mh = 0; mh < 2; ++mh)
#pragma unroll
          for (int j = 0; j < 4; ++j) {
            int row = bm0 + mh * 128 + (j * 2 + wm) * 16 + lg * 4;
#pragma unroll
            for (int r = 0; r < 4; ++r)
              out[(size_t)(row + r) * V_N + col] = acc[mh * 4 + j][nh * 2 + i][r] * scale;
          }
      }
    }
}

// ---------------- Fallback kernel 2: on-the-fly B generation (R0, proven) ------------
__global__ __launch_bounds__(256) void k2_synth_otf(
    const f16* __restrict__ A, float* __restrict__ out) {
  __shared__ __align__(16) f16 As[128 * 64];
  __shared__ __align__(16) f16 Bs[128 * 64];
  const int tid = threadIdx.x;
  const int bn0 = blockIdx.x * 128;
  const int bm0 = blockIdx.y * 128;
  const int lane = tid & 63, wid = tid >> 6;
  const int lr = lane & 15, lg = lane >> 4;
  const int wr = wid >> 1, wc = wid & 1;

  const int nloc = tid & 127;
  const int g = tid >> 7;
  const int t = bn0 + nloc;
  const float w0 = TWO_PI / (float)V_N;
  float cr, ci, r1c, r1s, r17c, r17s;
  {
    int a1 = (int)(((long long)(16 * g + 1) * t) % V_N);
    int a2 = (int)((long long)t % V_N);
    int a3 = (int)(((long long)17 * t) % V_N);
    __sincosf((float)a1 * w0, &ci, &cr);
    __sincosf((float)a2 * w0, &r1s, &r1c);
    __sincosf((float)a3 * w0, &r17s, &r17c);
  }

  f32x4 acc[4][4];
#pragma unroll
  for (int i = 0; i < 4; ++i)
#pragma unroll
    for (int j = 0; j < 4; ++j) acc[i][j] = (f32x4){0.f, 0.f, 0.f, 0.f};

  for (int s = 0; s < KC / 64; ++s) {
    f16x8 bch[4];
#pragma unroll
    for (int u = 0; u < 4; ++u)
#pragma unroll
      for (int p = 0; p < 4; ++p) {
        bch[u][2 * p]     = (f16)cr;
        bch[u][2 * p + 1] = (f16)(-ci);
        float rc = (u == 3 && p == 3) ? r17c : r1c;
        float rs = (u == 3 && p == 3) ? r17s : r1s;
        float nc = cr * rc - ci * rs;
        float ns = cr * rs + ci * rc;
        cr = nc; ci = ns;
      }
    __syncthreads();
#pragma unroll
    for (int ii = 0; ii < 4; ++ii) {
      int i = wid * 4 + ii;
      int q = i * 64 + lane;
      int m = q >> 3, cl = q & 7;
      int cg = cl ^ (m & 7);
      gload_lds16(A + (size_t)(bm0 + m) * KC + s * 64 + cg * 8, &As[i * 512]);
    }
#pragma unroll
    for (int u = 0; u < 4; ++u) {
      int c = 4 * g + u;
      *(f16x8*)&Bs[nloc * 64 + ((c ^ (nloc & 7)) << 3)] = bch[u];
    }
    __syncthreads();
#pragma unroll
    for (int kk = 0; kk < 2; ++kk) {
      const int cb = kk * 4 + lg;
      f16x8 av[4], bv[4];
#pragma unroll
      for (int mi = 0; mi < 4; ++mi) {
        int row = wr * 64 + mi * 16 + lr;
        av[mi] = *(const f16x8*)&As[row * 64 + ((cb ^ (row & 7)) << 3)];
      }
#pragma unroll
      for (int ni = 0; ni < 4; ++ni) {
        int col = wc * 64 + ni * 16 + lr;
        bv[ni] = *(const f16x8*)&Bs[col * 64 + ((cb ^ (col & 7)) << 3)];
      }
#pragma unroll
      for (int mi = 0; mi < 4; ++mi)
#pragma unroll
        for (int ni = 0; ni < 4; ++ni)
          acc[mi][ni] = __builtin_amdgcn_mfma_f32_16x16x32_f16(av[mi], bv[ni], acc[mi][ni], 0, 0, 0);
    }
  }
  const float scale = 2.0f / (float)V_N;
#pragma unroll
  for (int ni = 0; ni < 4; ++ni) {
    int col = bn0 + wc * 64 + ni * 16 + lr;
    if (col < V_N) {
#pragma unroll
      for (int mi = 0; mi < 4; ++mi)
#pragma unroll
        for (int r = 0; r < 4; ++r) {
          int row = bm0 + wr * 64 + mi * 16 + lg * 4 + r;
          out[(size_t)row * V_N + col] = acc[mi][ni][r] * scale;
        }
    }
  }
}

extern "C" void kernel_launch(void* const* d_in, const int* in_sizes, int n_in,
                              void* d_out, int out_size, void* d_ws, size_t ws_size,
                              hipStream_t stream) {
  const float* h = (const float*)d_in[0];
  const float* w = (const float*)d_in[1];
  float* out = (float*)d_out;

  const size_t B_BYTES = (size_t)V_PAD * KC * sizeof(f16);   // 51.6 MB
  const size_t A_BYTES = (size_t)MT * KC * sizeof(f16);      //  4.2 MB
  dim3 blk(256);

  if (ws_size >= B_BYTES + A_BYTES) {
    f16* Bt = (f16*)d_ws;
    f16* A  = (f16*)((char*)d_ws + B_BYTES);
    hipLaunchKernelGGL(k0_genB, dim3((V_PAD * 64) / 256), blk, 0, stream, Bt);
    hipLaunchKernelGGL(k1_proj, dim3(KC / 64, MT / 64), blk, 0, stream, h, w, A);
    hipLaunchKernelGGL(k2_8ph, dim3(NPAN * 16), dim3(512), 0, stream, A, Bt, out);
  } else {
    f16* A = (f16*)d_ws;
    hipLaunchKernelGGL(k1_proj, dim3(KC / 64, MT / 64), blk, 0, stream, h, w, A);
    hipLaunchKernelGGL(k2_synth_otf, dim3((V_N + 127) / 128, MT / 128), blk, 0, stream, A, out);
  }
}